// Round 5
// baseline (515.654 us; speedup 1.0000x reference)
//
#include <hip/hip_runtime.h>
#include <stdint.h>

#define S_LEN 2048
#define NH 16
#define EMB 1024

typedef __attribute__((ext_vector_type(8))) short bf16x8;
typedef __attribute__((ext_vector_type(4))) float floatx4;
typedef const __attribute__((address_space(1))) unsigned int* gas_u32p;
typedef __attribute__((address_space(3))) unsigned int* las_u32p;

static __device__ __forceinline__ void gld_lds16(const void* g, void* l) {
  __builtin_amdgcn_global_load_lds((gas_u32p)g, (las_u32p)l, 16, 0, 0);
}

static __device__ __forceinline__ unsigned short f2bf(float f) {
  unsigned int u = __float_as_uint(f);
  unsigned int r = (u + 0x7FFFu + ((u >> 16) & 1u)) >> 16;
  return (unsigned short)r;
}
static __device__ __forceinline__ unsigned short f2bf_fast(float f) {
  return (unsigned short)((__float_as_uint(f) + 0x8000u) >> 16);
}

// ---------------- cast X f32 -> bf16 ----------------
__global__ void cast_x_kernel(const float* __restrict__ x, unsigned short* __restrict__ out, int n4) {
  int i = blockIdx.x * blockDim.x + threadIdx.x;
  if (i >= n4) return;
  float4 v = ((const float4*)x)[i];
  ushort4 o;
  o.x = f2bf(v.x); o.y = f2bf(v.y); o.z = f2bf(v.z); o.w = f2bf(v.w);
  ((ushort4*)out)[i] = o;
}

// ---------------- transpose+cast up to 3 weights f32 -> WT bf16 ----------------
__global__ void transpose_cast3(const float* __restrict__ W0, const float* __restrict__ W1,
                                const float* __restrict__ W2, unsigned short* __restrict__ out) {
  __shared__ float tile[32][33];
  const float* in = (blockIdx.z == 0) ? W0 : ((blockIdx.z == 1) ? W1 : W2);
  unsigned short* o = out + (size_t)blockIdx.z * 1048576;
  int x = blockIdx.x * 32 + threadIdx.x;
  int y0 = blockIdx.y * 32 + threadIdx.y;
#pragma unroll
  for (int j = 0; j < 4; j++)
    tile[threadIdx.y + 8 * j][threadIdx.x] = in[(y0 + 8 * j) * EMB + x];
  __syncthreads();
  int x2 = blockIdx.y * 32 + threadIdx.x;
  int y2 = blockIdx.x * 32 + threadIdx.y;
#pragma unroll
  for (int j = 0; j < 4; j++)
    o[(y2 + 8 * j) * EMB + x2] = f2bf(tile[threadIdx.x][threadIdx.y + 8 * j]);
}

// ---------------- bias LUT: lut[h][delta+2048] ----------------
__global__ void build_lut_kernel(const float* __restrict__ rel_emb, float* __restrict__ lut) {
  int idx = blockIdx.x * blockDim.x + threadIdx.x;
  if (idx >= 4096) return;
  int delta = idx - 2048;
  int bucket = (delta > 0) ? 16 : 0;
  int rp = (delta < 0) ? -delta : delta;
  int bl;
  if (rp < 8) bl = rp;
  else bl = 8 + (rp >= 12) + (rp >= 16) + (rp >= 23) + (rp >= 32) + (rp >= 46) + (rp >= 64) + (rp >= 91);
  bucket += bl;
#pragma unroll
  for (int h = 0; h < NH; h++)
    lut[h * 4096 + idx] = rel_emb[bucket * NH + h];
}

// ---------------- GEMM Q/K: C[M,2048] = Xb @ [Wq|Wk]^T, bf16 out [B,H,S,D] ----------------
__global__ __launch_bounds__(256) void gemm_qk(const unsigned short* __restrict__ A,
                                               const unsigned short* __restrict__ BT,
                                               unsigned short* __restrict__ oQ,
                                               unsigned short* __restrict__ oK) {
  __shared__ __align__(16) unsigned short As[128 * 64];
  __shared__ __align__(16) unsigned short Bs[128 * 64];
  const int tid = threadIdx.x;
  const int wave = tid >> 6, lane = tid & 63;
  const int quad = lane >> 4, lm = lane & 15;
  const int wm = wave & 1, wn = wave >> 1;
  const int mBase = blockIdx.y * 128, nBase = blockIdx.x * 128;
  const int gg = (lane & 7) ^ (lane >> 3);
  const int srow = lane >> 3;
  floatx4 acc[4][4];
#pragma unroll
  for (int i = 0; i < 4; i++)
#pragma unroll
    for (int j = 0; j < 4; j++) acc[i][j] = (floatx4){0.f, 0.f, 0.f, 0.f};

  for (int kt = 0; kt < 16; kt++) {
    int k0 = kt * 64;
    __syncthreads();
#pragma unroll
    for (int c = 0; c < 4; c++) {
      int chunk = wave * 4 + c;
      int row = chunk * 8 + srow;
      gld_lds16(&A[(size_t)(mBase + row) * 1024 + k0 + gg * 8], &As[chunk * 512]);
      gld_lds16(&BT[(size_t)(nBase + row) * 1024 + k0 + gg * 8], &Bs[chunk * 512]);
    }
    __syncthreads();
#pragma unroll
    for (int hh = 0; hh < 2; hh++) {
      bf16x8 af[4], bfr[4];
#pragma unroll
      for (int i = 0; i < 4; i++)
        af[i] = *(const bf16x8*)&As[(wm * 64 + i * 16 + lm) * 64 + (((hh << 2) + quad) ^ (lm & 7)) * 8];
#pragma unroll
      for (int j = 0; j < 4; j++)
        bfr[j] = *(const bf16x8*)&Bs[(wn * 64 + j * 16 + lm) * 64 + (((hh << 2) + quad) ^ (lm & 7)) * 8];
#pragma unroll
      for (int i = 0; i < 4; i++)
#pragma unroll
        for (int j = 0; j < 4; j++)
          acc[i][j] = __builtin_amdgcn_mfma_f32_16x16x32_bf16(af[i], bfr[j], acc[i][j], 0, 0, 0);
    }
  }
  const int which = nBase >> 10;
#pragma unroll
  for (int i = 0; i < 4; i++)
#pragma unroll
    for (int j = 0; j < 4; j++)
#pragma unroll
      for (int r = 0; r < 4; r++) {
        int row = mBase + wm * 64 + i * 16 + quad * 4 + r;
        int col = nBase + wn * 64 + j * 16 + lm;
        int b = row >> 11, s = row & 2047;
        int cw = col & 1023;
        int h = cw >> 6, d = cw & 63;
        unsigned short v = f2bf(acc[i][j][r]);
        if (which == 0) oQ[(((size_t)(b * NH + h) * S_LEN + s) * 64) + d] = v;
        else            oK[(((size_t)(b * NH + h) * S_LEN + s) * 64) + d] = v;
      }
}

// ---------------- GEMM V (operand-swapped): writes V^T [B,H,D,S] with coalesced stores ----------------
__global__ __launch_bounds__(256) void gemm_v(const unsigned short* __restrict__ A,
                                              const unsigned short* __restrict__ BT,
                                              unsigned short* __restrict__ oV) {
  __shared__ __align__(16) unsigned short As[128 * 64];
  __shared__ __align__(16) unsigned short Bs[128 * 64];
  const int tid = threadIdx.x;
  const int wave = tid >> 6, lane = tid & 63;
  const int quad = lane >> 4, lm = lane & 15;
  const int wm = wave & 1, wn = wave >> 1;
  const int mBase = blockIdx.y * 128, nBase = blockIdx.x * 128;
  const int gg = (lane & 7) ^ (lane >> 3);
  const int srow = lane >> 3;
  floatx4 acc[4][4];
#pragma unroll
  for (int i = 0; i < 4; i++)
#pragma unroll
    for (int j = 0; j < 4; j++) acc[i][j] = (floatx4){0.f, 0.f, 0.f, 0.f};

  for (int kt = 0; kt < 16; kt++) {
    int k0 = kt * 64;
    __syncthreads();
#pragma unroll
    for (int c = 0; c < 4; c++) {
      int chunk = wave * 4 + c;
      int row = chunk * 8 + srow;
      gld_lds16(&A[(size_t)(mBase + row) * 1024 + k0 + gg * 8], &As[chunk * 512]);
      gld_lds16(&BT[(size_t)(nBase + row) * 1024 + k0 + gg * 8], &Bs[chunk * 512]);
    }
    __syncthreads();
#pragma unroll
    for (int hh = 0; hh < 2; hh++) {
      bf16x8 af[4], bfr[4];
#pragma unroll
      for (int i = 0; i < 4; i++)
        af[i] = *(const bf16x8*)&As[(wm * 64 + i * 16 + lm) * 64 + (((hh << 2) + quad) ^ (lm & 7)) * 8];
#pragma unroll
      for (int j = 0; j < 4; j++)
        bfr[j] = *(const bf16x8*)&Bs[(wn * 64 + j * 16 + lm) * 64 + (((hh << 2) + quad) ^ (lm & 7)) * 8];
      // swapped: C rows = BT rows (d), C cols = A rows (s)
#pragma unroll
      for (int i = 0; i < 4; i++)
#pragma unroll
        for (int j = 0; j < 4; j++)
          acc[i][j] = __builtin_amdgcn_mfma_f32_16x16x32_bf16(bfr[j], af[i], acc[i][j], 0, 0, 0);
    }
  }
#pragma unroll
  for (int i = 0; i < 4; i++)
#pragma unroll
    for (int j = 0; j < 4; j++)
#pragma unroll
      for (int r = 0; r < 4; r++) {
        int n = nBase + wn * 64 + j * 16 + quad * 4 + r;  // 0..1023: h,d
        int m = mBase + wm * 64 + i * 16 + lm;            // 0..4095: b,s
        int h = n >> 6, d = n & 63;
        int b = m >> 11, s = m & 2047;
        oV[(((size_t)(b * NH + h) * 64 + d) * S_LEN) + s] = f2bf(acc[i][j][r]);
      }
}

// ---------------- GEMM out-proj: f32 [M,1024] ----------------
__global__ __launch_bounds__(256) void gemm_out(const unsigned short* __restrict__ A,
                                                const unsigned short* __restrict__ BT,
                                                float* __restrict__ oF) {
  __shared__ __align__(16) unsigned short As[128 * 64];
  __shared__ __align__(16) unsigned short Bs[128 * 64];
  const int tid = threadIdx.x;
  const int wave = tid >> 6, lane = tid & 63;
  const int quad = lane >> 4, lm = lane & 15;
  const int wm = wave & 1, wn = wave >> 1;
  const int mBase = blockIdx.y * 128, nBase = blockIdx.x * 128;
  const int gg = (lane & 7) ^ (lane >> 3);
  const int srow = lane >> 3;
  floatx4 acc[4][4];
#pragma unroll
  for (int i = 0; i < 4; i++)
#pragma unroll
    for (int j = 0; j < 4; j++) acc[i][j] = (floatx4){0.f, 0.f, 0.f, 0.f};

  for (int kt = 0; kt < 16; kt++) {
    int k0 = kt * 64;
    __syncthreads();
#pragma unroll
    for (int c = 0; c < 4; c++) {
      int chunk = wave * 4 + c;
      int row = chunk * 8 + srow;
      gld_lds16(&A[(size_t)(mBase + row) * 1024 + k0 + gg * 8], &As[chunk * 512]);
      gld_lds16(&BT[(size_t)(nBase + row) * 1024 + k0 + gg * 8], &Bs[chunk * 512]);
    }
    __syncthreads();
#pragma unroll
    for (int hh = 0; hh < 2; hh++) {
      bf16x8 af[4], bfr[4];
#pragma unroll
      for (int i = 0; i < 4; i++)
        af[i] = *(const bf16x8*)&As[(wm * 64 + i * 16 + lm) * 64 + (((hh << 2) + quad) ^ (lm & 7)) * 8];
#pragma unroll
      for (int j = 0; j < 4; j++)
        bfr[j] = *(const bf16x8*)&Bs[(wn * 64 + j * 16 + lm) * 64 + (((hh << 2) + quad) ^ (lm & 7)) * 8];
#pragma unroll
      for (int i = 0; i < 4; i++)
#pragma unroll
        for (int j = 0; j < 4; j++)
          acc[i][j] = __builtin_amdgcn_mfma_f32_16x16x32_bf16(af[i], bfr[j], acc[i][j], 0, 0, 0);
    }
  }
#pragma unroll
  for (int i = 0; i < 4; i++)
#pragma unroll
    for (int j = 0; j < 4; j++)
#pragma unroll
      for (int r = 0; r < 4; r++) {
        int row = mBase + wm * 64 + i * 16 + quad * 4 + r;
        int col = nBase + wn * 64 + j * 16 + lm;
        oF[(size_t)row * 1024 + col] = acc[i][j][r];
      }
}

// ---------------- flash attention + fused position_bias writer ----------------
// flat grid 512, XCD-swizzled: xcd = i&7 hosts bh in {xcd*4..xcd*4+3} -> K/V stays in its L2.
__global__ __launch_bounds__(256) void attn_kernel(const unsigned short* __restrict__ Qb,
                                                   const unsigned short* __restrict__ Kb,
                                                   const unsigned short* __restrict__ Vtb,
                                                   const float* __restrict__ lut,
                                                   unsigned short* __restrict__ Ob,
                                                   float* __restrict__ bias_out) {
  __shared__ __align__(16) unsigned short Kl[64 * 64];
  __shared__ __align__(16) unsigned short Vl[64 * 64];
  __shared__ __align__(16) unsigned short Pl[4 * 16 * 68];
  const int tid = threadIdx.x;
  const int wave = tid >> 6, lane = tid & 63;
  const int quad = lane >> 4, lm = lane & 15;
  const int ii = blockIdx.x;
  const int bh = (ii & 7) * 4 + ((ii >> 3) & 3);
  const int qTile = (ii >> 5) * 128;
  const int b = bh >> 4, h = bh & 15;
  const unsigned short* Qp = Qb + (size_t)bh * S_LEN * 64;
  const unsigned short* Kp = Kb + (size_t)bh * S_LEN * 64;
  const unsigned short* Vp = Vtb + (size_t)bh * 64 * S_LEN;
  const float* lrow = lut + h * 4096;
  const float cneg = lrow[0], cpos = lrow[4095];
  const int gg = (lane & 7) ^ (lane >> 3);
  const int srow = lane >> 3;
  const int qw = qTile + wave * 32;
  const bool writeBias = (b == 0);
  float* bdst = bias_out + ((size_t)(h * S_LEN + qTile)) * S_LEN;

  bf16x8 aq[2][2];
#pragma unroll
  for (int g = 0; g < 2; g++)
#pragma unroll
    for (int hh = 0; hh < 2; hh++)
      aq[g][hh] = *(const bf16x8*)&Qp[(qw + g * 16 + lm) * 64 + hh * 32 + quad * 8];

  floatx4 accO[2][4];
#pragma unroll
  for (int g = 0; g < 2; g++)
#pragma unroll
    for (int d = 0; d < 4; d++) accO[g][d] = (floatx4){0.f, 0.f, 0.f, 0.f};
  float lp[2] = {0.f, 0.f};

  unsigned short* Pw = &Pl[wave * 16 * 68];

  for (int kt = 0; kt < 32; kt++) {
    int kBase = kt * 64;
    __syncthreads();
#pragma unroll
    for (int c = 0; c < 2; c++) {
      int chunk = wave * 2 + c;
      int row = chunk * 8 + srow;
      gld_lds16(&Kp[(size_t)(kBase + row) * 64 + gg * 8], &Kl[chunk * 512]);
      gld_lds16(&Vp[(size_t)row * S_LEN + kBase + gg * 8], &Vl[chunk * 512]);
    }
    __syncthreads();

    bool farTile = (kBase + 154 <= qTile) || (kBase >= qTile + 218);
    float cfar = (kBase < qTile) ? cneg : cpos;

    if (writeBias) {
      float* bt = bdst + kBase;
      if (farTile) {
        floatx4 cf4 = (floatx4){cfar, cfar, cfar, cfar};
#pragma unroll
        for (int e = 0; e < 8; e++) {
          int f = tid + e * 256;
          int qlo = f >> 4, kk = (f & 15) << 2;
          __builtin_nontemporal_store(cf4, (floatx4*)&bt[(size_t)qlo * S_LEN + kk]);
        }
      } else {
#pragma unroll
        for (int e = 0; e < 8; e++) {
          int f = tid + e * 256;
          int qlo = f >> 4, kk = (f & 15) << 2;
          const float* lr = lrow + (kBase + kk) - (qTile + qlo) + 2048;
          floatx4 v = (floatx4){lr[0], lr[1], lr[2], lr[3]};
          __builtin_nontemporal_store(v, (floatx4*)&bt[(size_t)qlo * S_LEN + kk]);
        }
      }
    }

    bf16x8 kf[4][2], vf[4][2];
#pragma unroll
    for (int nt = 0; nt < 4; nt++)
#pragma unroll
      for (int hh = 0; hh < 2; hh++) {
        int off = (nt * 16 + lm) * 64 + (((hh << 2) + quad) ^ (lm & 7)) * 8;
        kf[nt][hh] = *(const bf16x8*)&Kl[off];
        vf[nt][hh] = *(const bf16x8*)&Vl[off];
      }

#pragma unroll
    for (int g = 0; g < 2; g++) {
      int q = qw + g * 16 + lm;
      floatx4 s4[4];
#pragma unroll
      for (int nt = 0; nt < 4; nt++) {
        floatx4 z = (floatx4){0.f, 0.f, 0.f, 0.f};
        z = __builtin_amdgcn_mfma_f32_16x16x32_bf16(kf[nt][0], aq[g][0], z, 0, 0, 0);
        z = __builtin_amdgcn_mfma_f32_16x16x32_bf16(kf[nt][1], aq[g][1], z, 0, 0, 0);
        s4[nt] = z;
      }
      float psum = 0.f;
#pragma unroll
      for (int nt = 0; nt < 4; nt++) {
        union { unsigned short u[4]; uint2 v; } pk;
#pragma unroll
        for (int r = 0; r < 4; r++) {
          float sv;
          if (farTile) sv = s4[nt][r] + cfar;
          else {
            int kcol = kBase + nt * 16 + quad * 4 + r;
            sv = s4[nt][r] + __ldg(&lrow[kcol - q + 2048]);
          }
          float p = __expf(sv);
          psum += p;
          pk.u[r] = f2bf_fast(p);
        }
        *(uint2*)&Pw[lm * 68 + nt * 16 + quad * 4] = pk.v;
      }
      lp[g] += psum;
      bf16x8 pa0 = *(const bf16x8*)&Pw[lm * 68 + quad * 8];
      bf16x8 pa1 = *(const bf16x8*)&Pw[lm * 68 + 32 + quad * 8];
#pragma unroll
      for (int d = 0; d < 4; d++) {
        accO[g][d] = __builtin_amdgcn_mfma_f32_16x16x32_bf16(pa0, vf[d][0], accO[g][d], 0, 0, 0);
        accO[g][d] = __builtin_amdgcn_mfma_f32_16x16x32_bf16(pa1, vf[d][1], accO[g][d], 0, 0, 0);
      }
    }
  }
#pragma unroll
  for (int g = 0; g < 2; g++) {
    lp[g] += __shfl_xor(lp[g], 16, 64);
    lp[g] += __shfl_xor(lp[g], 32, 64);
  }
#pragma unroll
  for (int g = 0; g < 2; g++) {
    float linv[4];
#pragma unroll
    for (int r = 0; r < 4; r++) linv[r] = 1.f / __shfl(lp[g], quad * 4 + r, 64);
#pragma unroll
    for (int d = 0; d < 4; d++)
#pragma unroll
      for (int r = 0; r < 4; r++) {
        int q = qTile + wave * 32 + g * 16 + quad * 4 + r;
        int col = h * 64 + d * 16 + lm;
        Ob[((size_t)(b * S_LEN + q)) * 1024 + col] = f2bf_fast(accO[g][d][r] * linv[r]);
      }
  }
}

extern "C" void kernel_launch(void* const* d_in, const int* in_sizes, int n_in,
                              void* d_out, int out_size, void* d_ws, size_t ws_size,
                              hipStream_t stream) {
  const float* X   = (const float*)d_in[0];
  const float* Wq  = (const float*)d_in[1];
  const float* Wk  = (const float*)d_in[2];
  const float* Wv  = (const float*)d_in[3];
  const float* Wo  = (const float*)d_in[4];
  const float* rel = (const float*)d_in[5];
  float* out = (float*)d_out;           // [2,2048,1024]
  float* bias_out = out + 4194304;      // [1,16,2048,2048]

  char* ws = (char*)d_ws;
  unsigned short* Xb    = (unsigned short*)(ws);
  unsigned short* WqkvT = (unsigned short*)(ws + (size_t)(8u  << 20));  // 3 x 2MB
  unsigned short* WoT   = (unsigned short*)(ws + (size_t)(14u << 20));
  unsigned short* Qb    = (unsigned short*)(ws + (size_t)(16u << 20));
  unsigned short* Kb    = (unsigned short*)(ws + (size_t)(24u << 20));
  unsigned short* Vtb   = (unsigned short*)(ws + (size_t)(32u << 20));
  unsigned short* Ob    = (unsigned short*)(ws + (size_t)(40u << 20));
  float* lut            = (float*)(ws + (size_t)(48u << 20));

  cast_x_kernel<<<4096, 256, 0, stream>>>(X, Xb, 1048576);
  dim3 tb(32, 8);
  transpose_cast3<<<dim3(32, 32, 3), tb, 0, stream>>>(Wq, Wk, Wv, WqkvT);
  transpose_cast3<<<dim3(32, 32, 1), tb, 0, stream>>>(Wo, Wo, Wo, WoT);
  build_lut_kernel<<<16, 256, 0, stream>>>(rel, lut);

  gemm_qk<<<dim3(16, 32), 256, 0, stream>>>(Xb, WqkvT, Qb, Kb);
  gemm_v<<<dim3(8, 32), 256, 0, stream>>>(Xb, WqkvT + 2 * 1048576, Vtb);
  attn_kernel<<<512, 256, 0, stream>>>(Qb, Kb, Vtb, lut, Ob, bias_out);
  gemm_out<<<dim3(8, 32), 256, 0, stream>>>(Ob, WoT, out);
}